// Round 4
// baseline (5263.139 us; speedup 1.0000x reference)
//
#include <hip/hip_runtime.h>
#include <math.h>

// Problem constants (fixed by the reference).
#define TT   512
#define BI   12
#define HH   50
#define BB   8
#define BTOT 2048

// Block = 704 threads = 11 waves, 256 blocks (1/CU).
// R3 post-mortem: broadcast ds_read_b128 pays the full 1024B return path
// (~8 cyc); 1200 reads/step = 9600 cyc matched the measured 9300 cyc/step.
// Fix: each thread owns U=2 gate rows so every h read feeds 2x the FMAs.
//   waves 0-3  : layer-0. lane = 32 groups x 2 K-halves (s=l&1).
//                thread: rows 2g,2g+1; weights 2x(25 h + 6 x) = 62.
//   waves 4-10 : layer-1. lane = 16 groups x 4 K-quarters (s=l&3).
//                s<2 -> w_ih1 (vs h0), s>=2 -> w_hh1 (vs h1); 2x25 = 50 wts.
// Reduction: shfl_xor(1) (+ shfl_xor(2) for layer1); s==0 lane writes gates.
// Update phase: tid<400 -> (unit,batch) owns c0,c1 for both layers.
// Layers software-pipelined by one step (exact), as R2/R3.

__device__ __forceinline__ float sigm_(float v){ return 1.f/(1.f+__expf(-v)); }
__device__ __forceinline__ float tanh_(float v){ return 1.f - 2.f/(__expf(2.f*v)+1.f); }

__launch_bounds__(704, 2)
__global__ void lstm2_kernel(const float* __restrict__ x,
                             const float* __restrict__ w_ih0, const float* __restrict__ w_hh0,
                             const float* __restrict__ b_ih0, const float* __restrict__ b_hh0,
                             const float* __restrict__ w_ih1, const float* __restrict__ w_hh1,
                             const float* __restrict__ b_ih1, const float* __restrict__ b_hh1,
                             const float* __restrict__ w_out, const float* __restrict__ b_out,
                             float* __restrict__ out)
{
    const int tid = threadIdx.x;
    const int wv  = tid >> 6;
    const int l   = tid & 63;
    const int b0  = blockIdx.x * BB;
    const bool is0 = (wv < 4);

    __shared__ __align__(16) float h0s[HH*BB];        // h0[u][b]
    __shared__ __align__(16) float h1s[HH*BB];        // h1[u][b]
    __shared__ __align__(16) float g0s[4*HH*BB];      // gates0[r][b], r=k*50+u
    __shared__ __align__(16) float g1s[4*HH*BB];

    // ---- gate-compute role ----
    int s, g;
    if (is0) { s = l & 1; g = wv * 32 + (l >> 1); }
    else     { s = l & 3; g = (wv - 4) * 16 + (l >> 2); }
    const bool gact = (g < 100);
    const int gg = gact ? g : 99;          // clamp for uniform weight loads
    const int r0 = 2 * gg, r1 = 2 * gg + 1;

    float w0[25], w1[25], wx0[6], wx1[6];
    float bias0 = 0.f, bias1 = 0.f;
    const float* hbase;
    float* gdst;
    if (is0) {
        const float* wsrc = w_hh0 + s * 25;
        #pragma unroll
        for (int j = 0; j < 25; j++) { w0[j] = wsrc[r0 * HH + j]; w1[j] = wsrc[r1 * HH + j]; }
        #pragma unroll
        for (int i = 0; i < 6; i++)  { wx0[i] = w_ih0[r0 * BI + s * 6 + i];
                                       wx1[i] = w_ih0[r1 * BI + s * 6 + i]; }
        if (s == 0) { bias0 = b_ih0[r0] + b_hh0[r0]; bias1 = b_ih0[r1] + b_hh0[r1]; }
        hbase = h0s + s * 25 * BB;
        gdst  = g0s;
    } else {
        const float* wsrc = ((s < 2) ? w_ih1 : w_hh1) + (s & 1) * 25;
        #pragma unroll
        for (int j = 0; j < 25; j++) { w0[j] = wsrc[r0 * HH + j]; w1[j] = wsrc[r1 * HH + j]; }
        if (s == 0) { bias0 = b_ih1[r0] + b_hh1[r0]; bias1 = b_ih1[r1] + b_hh1[r1]; }
        hbase = ((s < 2) ? h0s : h1s) + (s & 1) * 25 * BB;
        gdst  = g1s;
    }

    // ---- update role: tid<400 owns (unit uu, batch ub) for BOTH layers ----
    const int  uu   = tid >> 3, ub = tid & 7;
    const bool updt = (tid < 400);
    float cc0 = 0.f, cc1 = 0.f;

    if (tid < HH * BB) { h0s[tid] = 0.f; h1s[tid] = 0.f; }
    __syncthreads();

    for (int t = 0; t <= TT; t++) {
        const bool doit = is0 ? (t < TT) : (t >= 1);
        if (doit) {
            float a0[BB], a1[BB];
            #pragma unroll
            for (int b = 0; b < BB; b++) { a0[b] = bias0; a1[b] = bias1; }

            if (is0) {  // input projection first: global loads issue early
                #pragma unroll
                for (int b = 0; b < BB; b++) {
                    const float* xp = x + ((size_t)(b0 + b) * TT + t) * BI + s * 6;
                    const float2 x0 = ((const float2*)xp)[0];
                    const float2 x1 = ((const float2*)xp)[1];
                    const float2 x2 = ((const float2*)xp)[2];
                    a0[b] += wx0[0]*x0.x + wx0[1]*x0.y + wx0[2]*x1.x
                           + wx0[3]*x1.y + wx0[4]*x2.x + wx0[5]*x2.y;
                    a1[b] += wx1[0]*x0.x + wx1[1]*x0.y + wx1[2]*x1.x
                           + wx1[3]*x1.y + wx1[4]*x2.x + wx1[5]*x2.y;
                }
            }
            // recurrent part: 2 broadcast b128 reads per j feed 16 FMAs
            #pragma unroll
            for (int jj = 0; jj < 25; jj++) {
                const float4 ha = *(const float4*)(hbase + jj * BB);
                const float4 hb = *(const float4*)(hbase + jj * BB + 4);
                const float q0 = w0[jj], q1 = w1[jj];
                a0[0] += q0*ha.x; a0[1] += q0*ha.y; a0[2] += q0*ha.z; a0[3] += q0*ha.w;
                a0[4] += q0*hb.x; a0[5] += q0*hb.y; a0[6] += q0*hb.z; a0[7] += q0*hb.w;
                a1[0] += q1*ha.x; a1[1] += q1*ha.y; a1[2] += q1*ha.z; a1[3] += q1*ha.w;
                a1[4] += q1*hb.x; a1[5] += q1*hb.y; a1[6] += q1*hb.z; a1[7] += q1*hb.w;
            }
            // K-split reduction across the lane group
            #pragma unroll
            for (int b = 0; b < BB; b++) {
                a0[b] += __shfl_xor(a0[b], 1, 64);
                a1[b] += __shfl_xor(a1[b], 1, 64);
            }
            if (!is0) {
                #pragma unroll
                for (int b = 0; b < BB; b++) {
                    a0[b] += __shfl_xor(a0[b], 2, 64);
                    a1[b] += __shfl_xor(a1[b], 2, 64);
                }
            }
            if (gact && s == 0) {
                *(float4*)(gdst + r0 * BB    ) = make_float4(a0[0], a0[1], a0[2], a0[3]);
                *(float4*)(gdst + r0 * BB + 4) = make_float4(a0[4], a0[5], a0[6], a0[7]);
                *(float4*)(gdst + r1 * BB    ) = make_float4(a1[0], a1[1], a1[2], a1[3]);
                *(float4*)(gdst + r1 * BB + 4) = make_float4(a1[4], a1[5], a1[6], a1[7]);
            }
        }
        __syncthreads();

        if (updt) {
            const int base = uu * BB + ub;
            if (t < TT) {
                const float iv = sigm_(g0s[0 * HH * BB + base]);
                const float fv = sigm_(g0s[1 * HH * BB + base]);
                const float gv = tanh_(g0s[2 * HH * BB + base]);
                const float ov = sigm_(g0s[3 * HH * BB + base]);
                cc0 = fv * cc0 + iv * gv;
                h0s[base] = ov * tanh_(cc0);
            }
            if (t >= 1) {
                const float iv = sigm_(g1s[0 * HH * BB + base]);
                const float fv = sigm_(g1s[1 * HH * BB + base]);
                const float gv = tanh_(g1s[2 * HH * BB + base]);
                const float ov = sigm_(g1s[3 * HH * BB + base]);
                cc1 = fv * cc1 + iv * gv;
                h1s[base] = ov * tanh_(cc1);
            }
        }
        __syncthreads();
    }

    // ---- epilogue: sigmoid(h1[T-1] . w_out + b_out) ----
    if (tid < BB) {
        float sum = b_out[0];
        #pragma unroll
        for (int j = 0; j < HH; j++) sum += w_out[j] * h1s[j * BB + tid];
        out[b0 + tid] = sigm_(sum);
    }
}

extern "C" void kernel_launch(void* const* d_in, const int* in_sizes, int n_in,
                              void* d_out, int out_size, void* d_ws, size_t ws_size,
                              hipStream_t stream) {
    const float* x     = (const float*)d_in[0];
    const float* w_ih0 = (const float*)d_in[1];
    const float* w_hh0 = (const float*)d_in[2];
    const float* b_ih0 = (const float*)d_in[3];
    const float* b_hh0 = (const float*)d_in[4];
    const float* w_ih1 = (const float*)d_in[5];
    const float* w_hh1 = (const float*)d_in[6];
    const float* b_ih1 = (const float*)d_in[7];
    const float* b_hh1 = (const float*)d_in[8];
    const float* w_out = (const float*)d_in[9];
    const float* b_out = (const float*)d_in[10];
    float* out = (float*)d_out;

    dim3 grid(BTOT / BB);   // 256 blocks -> 1 per CU
    dim3 block(704);        // 11 waves: 4 layer-0 + 7 layer-1
    lstm2_kernel<<<grid, block, 0, stream>>>(x, w_ih0, w_hh0, b_ih0, b_hh0,
                                             w_ih1, w_hh1, b_ih1, b_hh1,
                                             w_out, b_out, out);
}

// Round 5
// 885.627 us; speedup vs baseline: 5.9428x; 5.9428x over previous
//
#include <hip/hip_runtime.h>
#include <math.h>

// ---- problem constants ----
#define TT   512
#define BI   12
#define HH   50
#define BB   8     // batch per block
#define BTOT 2048
#define NT   13    // M-tiles of 16 rows over 208 (= 52 units x 4 gates, padded)

// MFMA fp16 LSTM. Row order r = u*4 + g so one C-tile lane holds all 4 gates
// of one (unit, batch): full cell update stays in registers. B = [x;h] lives
// in LDS in fragment order [k>>3][n][k&7] (half), so a wave's B-frag load is
// one conflict-free ds_read_b128 at base + kblock*1024 + lane*16.
// Layer-0 B (K=64):  rows 0-11 x_t, 12-61 h0, 62 ones (bias col), 63 zero.
// Layer-1 B (K=128): rows 0-49 h0, 50-63 zero, 64-113 h1, 114 ones, rest 0.
// Ping-pong buffers: iter t reads buf[t&1], writes buf[1-(t&1)] -> 1 barrier.
// Layer pipeline (exact): iter t: l0 -> h0[t]; l1 -> h1[t-1]; t = 0..TT.

typedef _Float16 half8 __attribute__((ext_vector_type(8)));
typedef float    f4    __attribute__((ext_vector_type(4)));

__device__ __forceinline__ float sigm_(float v){ return 1.f/(1.f+__expf(-v)); }
__device__ __forceinline__ float tanh_(float v){ return 1.f - 2.f/(__expf(2.f*v)+1.f); }

__launch_bounds__(1024)
__global__ void lstm2_kernel(const float* __restrict__ x,
                             const float* __restrict__ w_ih0, const float* __restrict__ w_hh0,
                             const float* __restrict__ b_ih0, const float* __restrict__ b_hh0,
                             const float* __restrict__ w_ih1, const float* __restrict__ w_hh1,
                             const float* __restrict__ b_ih1, const float* __restrict__ b_hh1,
                             const float* __restrict__ w_out, const float* __restrict__ b_out,
                             float* __restrict__ out)
{
    const int tid   = threadIdx.x;
    const int wv    = tid >> 6;          // 0..15
    const int lane  = tid & 63;
    const int layer = wv >> 3;           // 0 or 1
    const int w8    = wv & 7;
    const int b0    = blockIdx.x * BB;
    // 13 tiles over 8 waves per layer: waves 0-4 take 2 tiles, 5-7 take 1.
    const int t0     = (w8 < 5) ? 2 * w8 : (5 + w8);
    const int ntiles = (w8 < 5) ? 2 : 1;

    __shared__ __align__(16) _Float16 B0s[2][64  * 16];
    __shared__ __align__(16) _Float16 B1s[2][128 * 16];

    // ---- load step-invariant A fragments (W in fragment layout) ----
    // A[m=lane&15][k=quad*8+j]; row reorder: m -> (u_local=m>>2, gate=m&3).
    const int m  = lane & 15;
    const int q  = lane >> 4;
    half8 af[2][4];
    #pragma unroll
    for (int s = 0; s < 2; s++) {
        #pragma unroll
        for (int kb = 0; kb < 4; kb++) {
            #pragma unroll
            for (int j = 0; j < 8; j++) {
                float v = 0.f;
                if (s < ntiles && (layer == 1 || kb < 2)) {
                    const int T  = t0 + s;
                    const int u  = T * 4 + (m >> 2);
                    const int g  = m & 3;
                    const int kg = kb * 32 + q * 8 + j;
                    if (u < HH) {
                        const int r = g * HH + u;
                        if (layer == 0) {
                            if      (kg < 12) v = w_ih0[r * BI + kg];
                            else if (kg < 62) v = w_hh0[r * HH + (kg - 12)];
                            else if (kg == 62) v = b_ih0[r] + b_hh0[r];
                        } else {
                            if      (kg < 50)  v = w_ih1[r * HH + kg];
                            else if (kg < 64)  v = 0.f;
                            else if (kg < 114) v = w_hh1[r * HH + (kg - 64)];
                            else if (kg == 114) v = b_ih1[r] + b_hh1[r];
                        }
                    }
                }
                af[s][kb][j] = (_Float16)v;
            }
        }
    }

    // ---- init LDS: zero both buffers, ones rows, x[0] ----
    for (int i = tid; i < 2 * 64 * 16;  i += 1024) (&B0s[0][0])[i] = (_Float16)0.f;
    for (int i = tid; i < 2 * 128 * 16; i += 1024) (&B1s[0][0])[i] = (_Float16)0.f;
    __syncthreads();
    if (tid < 16) {                       // bias (ones) rows, both buffers
        B0s[0][7  * 128 + tid * 8 + 6] = (_Float16)1.f;
        B0s[1][7  * 128 + tid * 8 + 6] = (_Float16)1.f;
        B1s[0][14 * 128 + tid * 8 + 2] = (_Float16)1.f;
        B1s[1][14 * 128 + tid * 8 + 2] = (_Float16)1.f;
    }
    if (tid < 96) {                       // x[0] -> buf0
        const int xb = tid / 12, xi = tid - xb * 12;
        B0s[0][(xi >> 3) * 128 + xb * 8 + (xi & 7)] =
            (_Float16)x[((size_t)(b0 + xb) * TT + 0) * BI + xi];
    }
    float cst0 = 0.f, cst1 = 0.f;         // cell state for tile slots 0,1
    __syncthreads();

    const int un  = t0 * 4 + (lane >> 4); // unit for slot 0 (slot1: +4)
    const int n   = lane & 15;

    for (int t = 0; t <= TT; t++) {
        const int p = t & 1;

        // prefetch x[t+1] (global, independent of recurrence)
        float xpre = 0.f; int xb = 0, xi = 0;
        const bool do_x = (tid < 96) && (t + 1 < TT);
        if (do_x) {
            xb = tid / 12; xi = tid - xb * 12;
            xpre = x[((size_t)(b0 + xb) * TT + (t + 1)) * BI + xi];
        }

        const bool active = layer ? (t >= 1) : (t < TT);
        if (active) {
            f4 acc0 = {0.f, 0.f, 0.f, 0.f};
            f4 acc1 = {0.f, 0.f, 0.f, 0.f};
            if (layer == 0) {
                const _Float16* Bp = &B0s[p][0];
                #pragma unroll
                for (int kb = 0; kb < 2; kb++) {
                    const half8 bf = *(const half8*)(Bp + kb * 512 + lane * 8);
                    acc0 = __builtin_amdgcn_mfma_f32_16x16x32_f16(af[0][kb], bf, acc0, 0, 0, 0);
                    if (ntiles > 1)
                        acc1 = __builtin_amdgcn_mfma_f32_16x16x32_f16(af[1][kb], bf, acc1, 0, 0, 0);
                }
            } else {
                const _Float16* Bp = &B1s[p][0];
                #pragma unroll
                for (int kb = 0; kb < 4; kb++) {
                    const half8 bf = *(const half8*)(Bp + kb * 512 + lane * 8);
                    acc0 = __builtin_amdgcn_mfma_f32_16x16x32_f16(af[0][kb], bf, acc0, 0, 0, 0);
                    if (ntiles > 1)
                        acc1 = __builtin_amdgcn_mfma_f32_16x16x32_f16(af[1][kb], bf, acc1, 0, 0, 0);
                }
            }
            // ---- in-register cell update; lane owns (unit, batch) ----
            #pragma unroll
            for (int s = 0; s < 2; s++) {
                if (s < ntiles) {
                    const f4 a = s ? acc1 : acc0;
                    const int u = un + s * 4;
                    const float iv = sigm_(a[0]);
                    const float fv = sigm_(a[1]);
                    const float gv = tanh_(a[2]);
                    const float ov = sigm_(a[3]);
                    float& cs = s ? cst1 : cst0;
                    cs = fv * cs + iv * gv;
                    const float h = ov * tanh_(cs);
                    if (u < HH && n < 8) {
                        const _Float16 hh = (_Float16)h;
                        if (layer == 0) {
                            const int k0 = 12 + u;   // h0 recurrence row in B0
                            B0s[1 - p][(k0 >> 3) * 128 + n * 8 + (k0 & 7)] = hh;
                            B1s[1 - p][(u  >> 3) * 128 + n * 8 + (u  & 7)] = hh;
                        } else {
                            const int k1 = 64 + u;   // h1 recurrence row in B1
                            B1s[1 - p][(k1 >> 3) * 128 + n * 8 + (k1 & 7)] = hh;
                        }
                    }
                }
            }
        }
        if (do_x)
            B0s[1 - p][(xi >> 3) * 128 + xb * 8 + (xi & 7)] = (_Float16)xpre;
        __syncthreads();
    }

    // ---- epilogue: sigmoid(h1[TT-1] . w_out + b_out); h1[TT-1] is in buf1 ----
    if (tid < BB) {
        float s = b_out[0];
        #pragma unroll
        for (int u = 0; u < HH; u++) {
            const int k1 = 64 + u;
            s += w_out[u] * (float)B1s[1][(k1 >> 3) * 128 + tid * 8 + (k1 & 7)];
        }
        out[b0 + tid] = sigm_(s);
    }
}

extern "C" void kernel_launch(void* const* d_in, const int* in_sizes, int n_in,
                              void* d_out, int out_size, void* d_ws, size_t ws_size,
                              hipStream_t stream) {
    const float* x     = (const float*)d_in[0];
    const float* w_ih0 = (const float*)d_in[1];
    const float* w_hh0 = (const float*)d_in[2];
    const float* b_ih0 = (const float*)d_in[3];
    const float* b_hh0 = (const float*)d_in[4];
    const float* w_ih1 = (const float*)d_in[5];
    const float* w_hh1 = (const float*)d_in[6];
    const float* b_ih1 = (const float*)d_in[7];
    const float* b_hh1 = (const float*)d_in[8];
    const float* w_out = (const float*)d_in[9];
    const float* b_out = (const float*)d_in[10];
    float* out = (float*)d_out;

    dim3 grid(BTOT / BB);   // 256 blocks -> 1 per CU
    dim3 block(1024);       // 16 waves: 8 layer-0 + 8 layer-1 MFMA waves
    lstm2_kernel<<<grid, block, 0, stream>>>(x, w_ih0, w_hh0, b_ih0, b_hh0,
                                             w_ih1, w_hh1, b_ih1, b_hh1,
                                             w_out, b_out, out);
}

// Round 6
// 449.404 us; speedup vs baseline: 11.7114x; 1.9707x over previous
//
#include <hip/hip_runtime.h>
#include <math.h>

// ---- problem constants ----
#define TT   512
#define BI   12
#define HH   50
#define BB   8     // batch per block
#define BTOT 2048

// MFMA fp16 LSTM (R5 structure) + R6 fixes:
//  - all sigmoid/tanh divisions -> v_rcp_f32 (R5 emitted full IEEE div
//    sequences: ~10 x 7 instrs per wave-step of pure bloat)
//  - update-slot merge: slot1's useful n<8 columns are shuffled (xor 8) into
//    the dead n>=8 lanes, so each wave runs ONE activation bundle on 64
//    useful lanes instead of two bundles on 32.
//  - per-parity LDS pointers precomputed outside the loop.
// Layout (unchanged, verified R5): row r = u*4+gate so each lane's f4 acc
// holds all 4 gates of one (unit,batch) -> cell update fully in-register.
// B = [x;h] in LDS fragment order [k>>3][n][k&7]; ping-pong buffers; one
// barrier per step; layers software-pipelined by one step (exact).

typedef _Float16 half8 __attribute__((ext_vector_type(8)));
typedef float    f4    __attribute__((ext_vector_type(4)));

__device__ __forceinline__ float sigm_(float v) {
    // 1/(1+e^-v): v_mul, v_exp, v_add, v_rcp
    return __builtin_amdgcn_rcpf(1.f + __expf(-v));
}
__device__ __forceinline__ float tanh_(float v) {
    // 1 - 2/(e^2v+1): v_mul, v_exp, v_add, v_rcp, v_fma
    return 1.f - 2.f * __builtin_amdgcn_rcpf(__expf(2.f * v) + 1.f);
}

__launch_bounds__(1024)
__global__ void lstm2_kernel(const float* __restrict__ x,
                             const float* __restrict__ w_ih0, const float* __restrict__ w_hh0,
                             const float* __restrict__ b_ih0, const float* __restrict__ b_hh0,
                             const float* __restrict__ w_ih1, const float* __restrict__ w_hh1,
                             const float* __restrict__ b_ih1, const float* __restrict__ b_hh1,
                             const float* __restrict__ w_out, const float* __restrict__ b_out,
                             float* __restrict__ out)
{
    const int tid   = threadIdx.x;
    const int wv    = tid >> 6;          // 0..15
    const int lane  = tid & 63;
    const int layer = wv >> 3;           // 0 or 1
    const int w8    = wv & 7;
    const int b0    = blockIdx.x * BB;
    // 13 M-tiles per layer over 8 waves: waves 0-4 take 2, waves 5-7 take 1.
    const int t0     = (w8 < 5) ? 2 * w8 : (5 + w8);
    const int ntiles = (w8 < 5) ? 2 : 1;

    __shared__ __align__(16) _Float16 B0s[2][64  * 16];
    __shared__ __align__(16) _Float16 B1s[2][128 * 16];

    // ---- step-invariant A fragments (weights, fragment layout) ----
    const int m = lane & 15;
    const int q = lane >> 4;
    half8 af[2][4];
    #pragma unroll
    for (int s = 0; s < 2; s++) {
        #pragma unroll
        for (int kb = 0; kb < 4; kb++) {
            #pragma unroll
            for (int j = 0; j < 8; j++) {
                float v = 0.f;
                if (s < ntiles && (layer == 1 || kb < 2)) {
                    const int T  = t0 + s;
                    const int u  = T * 4 + (m >> 2);
                    const int g  = m & 3;
                    const int kg = kb * 32 + q * 8 + j;
                    if (u < HH) {
                        const int r = g * HH + u;
                        if (layer == 0) {
                            if      (kg < 12)  v = w_ih0[r * BI + kg];
                            else if (kg < 62)  v = w_hh0[r * HH + (kg - 12)];
                            else if (kg == 62) v = b_ih0[r] + b_hh0[r];
                        } else {
                            if      (kg < 50)  v = w_ih1[r * HH + kg];
                            else if (kg < 64)  v = 0.f;
                            else if (kg < 114) v = w_hh1[r * HH + (kg - 64)];
                            else if (kg == 114) v = b_ih1[r] + b_hh1[r];
                        }
                    }
                }
                af[s][kb][j] = (_Float16)v;
            }
        }
    }

    // ---- init LDS ----
    for (int i = tid; i < 2 * 64 * 16;  i += 1024) (&B0s[0][0])[i] = (_Float16)0.f;
    for (int i = tid; i < 2 * 128 * 16; i += 1024) (&B1s[0][0])[i] = (_Float16)0.f;
    __syncthreads();
    if (tid < 16) {                       // bias (ones) rows, both parities
        B0s[0][7  * 128 + tid * 8 + 6] = (_Float16)1.f;
        B0s[1][7  * 128 + tid * 8 + 6] = (_Float16)1.f;
        B1s[0][14 * 128 + tid * 8 + 2] = (_Float16)1.f;
        B1s[1][14 * 128 + tid * 8 + 2] = (_Float16)1.f;
    }
    const int xb = tid / 12, xi = tid - xb * 12;           // loop-invariant
    const int xoff = (xi >> 3) * 128 + xb * 8 + (xi & 7);
    if (tid < 96)                          // x[0] -> parity 0
        B0s[0][xoff] = (_Float16)x[((size_t)(b0 + xb) * TT + 0) * BI + xi];
    __syncthreads();

    // ---- merged update role: lane owns (u_m, bcol) ----
    const int n16  = lane & 15;
    const int slot = n16 >> 3;            // 0: own acc0; 1: partner's acc1
    const int bcol = n16 & 7;
    const int u_m  = (t0 + slot) * 4 + q;
    const bool wvalid = (u_m < HH) && (slot == 0 || ntiles == 2);
    float cm = 0.f;                        // cell state for (u_m, bcol)

    // ---- per-parity pointers (precomputed; 1 cndmask select per use) ----
    const _Float16* rd0 = (layer ? &B1s[0][0] : &B0s[0][0]) + lane * 8;
    const _Float16* rd1 = (layer ? &B1s[1][0] : &B0s[1][0]) + lane * 8;
    // h write destinations (write parity = 1-p)
    const int k0 = 12 + u_m;              // h0 row in B0
    const int k1 = 64 + u_m;              // h1 row in B1
    const int offA = layer ? ((k1 >> 3) * 128 + bcol * 8 + (k1 & 7))
                           : ((k0 >> 3) * 128 + bcol * 8 + (k0 & 7));
    const int offB = (u_m >> 3) * 128 + bcol * 8 + (u_m & 7);   // h0 row in B1 (layer0)
    _Float16* wA0 = (layer ? &B1s[0][0] : &B0s[0][0]) + offA;   // parity-0 dest
    _Float16* wA1 = (layer ? &B1s[1][0] : &B0s[1][0]) + offA;
    _Float16* wB0 = &B1s[0][0] + offB;
    _Float16* wB1 = &B1s[1][0] + offB;
    _Float16* xd0 = &B0s[0][0] + xoff;
    _Float16* xd1 = &B0s[1][0] + xoff;

    for (int t = 0; t <= TT; t++) {
        const int p = t & 1;

        // prefetch x[t+1] (independent of recurrence)
        float xpre = 0.f;
        const bool do_x = (tid < 96) && (t + 1 < TT);
        if (do_x) xpre = x[((size_t)(b0 + xb) * TT + (t + 1)) * BI + xi];

        const bool active = layer ? (t >= 1) : (t < TT);
        if (active) {
            f4 acc0 = {0.f, 0.f, 0.f, 0.f};
            f4 acc1 = {0.f, 0.f, 0.f, 0.f};
            const _Float16* Bp = p ? rd1 : rd0;
            if (layer == 0) {
                #pragma unroll
                for (int kb = 0; kb < 2; kb++) {
                    const half8 bf = *(const half8*)(Bp + kb * 512);
                    acc0 = __builtin_amdgcn_mfma_f32_16x16x32_f16(af[0][kb], bf, acc0, 0, 0, 0);
                    if (ntiles > 1)
                        acc1 = __builtin_amdgcn_mfma_f32_16x16x32_f16(af[1][kb], bf, acc1, 0, 0, 0);
                }
            } else {
                #pragma unroll
                for (int kb = 0; kb < 4; kb++) {
                    const half8 bf = *(const half8*)(Bp + kb * 512);
                    acc0 = __builtin_amdgcn_mfma_f32_16x16x32_f16(af[0][kb], bf, acc0, 0, 0, 0);
                    if (ntiles > 1)
                        acc1 = __builtin_amdgcn_mfma_f32_16x16x32_f16(af[1][kb], bf, acc1, 0, 0, 0);
                }
            }
            // ---- slot merge: one activation bundle per wave ----
            f4 am;
            #pragma unroll
            for (int i = 0; i < 4; i++) {
                const float o = __shfl_xor(acc1[i], 8, 64);
                am[i] = (slot == 0) ? acc0[i] : o;
            }
            const float iv = sigm_(am[0]);
            const float fv = sigm_(am[1]);
            const float gv = tanh_(am[2]);
            const float ov = sigm_(am[3]);
            cm = fv * cm + iv * gv;
            const float h = ov * tanh_(cm);
            if (wvalid) {
                const _Float16 hh = (_Float16)h;
                *(p ? wA0 : wA1) = hh;           // write parity = 1-p
                if (layer == 0) *(p ? wB0 : wB1) = hh;
            }
        }
        if (do_x) *(p ? xd0 : xd1) = (_Float16)xpre;
        __syncthreads();
    }

    // ---- epilogue: sigmoid(h1[TT-1] . w_out + b_out); h1[TT-1] in parity 1 ----
    if (tid < BB) {
        float s = b_out[0];
        #pragma unroll
        for (int u = 0; u < HH; u++) {
            const int kk = 64 + u;
            s += w_out[u] * (float)B1s[1][(kk >> 3) * 128 + tid * 8 + (kk & 7)];
        }
        out[b0 + tid] = sigm_(s);
    }
}

extern "C" void kernel_launch(void* const* d_in, const int* in_sizes, int n_in,
                              void* d_out, int out_size, void* d_ws, size_t ws_size,
                              hipStream_t stream) {
    const float* x     = (const float*)d_in[0];
    const float* w_ih0 = (const float*)d_in[1];
    const float* w_hh0 = (const float*)d_in[2];
    const float* b_ih0 = (const float*)d_in[3];
    const float* b_hh0 = (const float*)d_in[4];
    const float* w_ih1 = (const float*)d_in[5];
    const float* w_hh1 = (const float*)d_in[6];
    const float* b_ih1 = (const float*)d_in[7];
    const float* b_hh1 = (const float*)d_in[8];
    const float* w_out = (const float*)d_in[9];
    const float* b_out = (const float*)d_in[10];
    float* out = (float*)d_out;

    dim3 grid(BTOT / BB);   // 256 blocks -> 1 per CU
    dim3 block(1024);       // 16 waves: 8 layer-0 + 8 layer-1
    lstm2_kernel<<<grid, block, 0, stream>>>(x, w_ih0, w_hh0, b_ih0, b_hh0,
                                             w_ih1, w_hh1, b_ih1, b_hh1,
                                             w_out, b_out, out);
}